// Round 1
// baseline (2054.053 us; speedup 1.0000x reference)
//
#include <hip/hip_runtime.h>

#define N_TOKEN 8192
#define N_EMBED 512
#define T_TOKENS 16384

// ---------- helpers ----------
__device__ __forceinline__ unsigned int fkey(float f) {
  unsigned int u = __float_as_uint(f);
  return (u & 0x80000000u) ? ~u : (u | 0x80000000u);
}

// ---------- K1: h[k] = 0.5*||key_w[k]||^2 ----------
__global__ void k_hnorm(const float* __restrict__ key_w, float* __restrict__ h) {
  int code = blockIdx.x * 4 + (threadIdx.x >> 6);
  int lane = threadIdx.x & 63;
  const float4* row = reinterpret_cast<const float4*>(key_w + (size_t)code * N_EMBED);
  float s = 0.f;
  float4 v0 = row[lane];
  float4 v1 = row[lane + 64];
  s += v0.x*v0.x + v0.y*v0.y + v0.z*v0.z + v0.w*v0.w;
  s += v1.x*v1.x + v1.y*v1.y + v1.z*v1.z + v1.w*v1.w;
  #pragma unroll
  for (int off = 32; off; off >>= 1) s += __shfl_down(s, off);
  if (lane == 0) h[code] = 0.5f * s;
}

// ---------- K2: tiled f32 GEMM (x . key^T) fused with argmin ----------
// score[t][k] = 0.5||k_k||^2 - x_t.k_k   (same argmin as squared distance)
#define BT 128
#define BK 128
#define DC 32

__global__ __launch_bounds__(256, 2) void k_gemm_argmin(
    const float* __restrict__ x, const float* __restrict__ key_w,
    const float* __restrict__ h, unsigned long long* __restrict__ best) {
  __shared__ float4 XS[BT * 8];  // [row][f4slot], slot XOR-swizzled by row&7
  __shared__ float4 KS[BK * 8];

  const int kb = blockIdx.x, tb = blockIdx.y;
  const int t0 = tb * BT, k0 = kb * BK;
  const int tid = threadIdx.x;
  const int tx = tid & 15;        // col group (16)
  const int tyg = tid >> 4;       // row group (16)

  float acc[8][8];
  #pragma unroll
  for (int i = 0; i < 8; ++i)
    #pragma unroll
    for (int j = 0; j < 8; ++j) acc[i][j] = 0.f;

  for (int dc = 0; dc < N_EMBED; dc += DC) {
    __syncthreads();  // protect LDS reuse from previous chunk
    #pragma unroll
    for (int l = 0; l < 4; ++l) {
      int li = l * 256 + tid;
      int row = li >> 3, c4 = li & 7;
      XS[row * 8 + (c4 ^ (row & 7))] =
          *reinterpret_cast<const float4*>(x + (size_t)(t0 + row) * N_EMBED + dc + c4 * 4);
      KS[row * 8 + (c4 ^ (row & 7))] =
          *reinterpret_cast<const float4*>(key_w + (size_t)(k0 + row) * N_EMBED + dc + c4 * 4);
    }
    __syncthreads();
    #pragma unroll
    for (int d4 = 0; d4 < 8; ++d4) {
      float4 a[8], b[8];
      #pragma unroll
      for (int j = 0; j < 8; ++j) {
        a[j] = XS[(tyg + 16 * j) * 8 + (d4 ^ (tyg & 7))];
        b[j] = KS[(tx  + 16 * j) * 8 + (d4 ^ (tx  & 7))];
      }
      #pragma unroll
      for (int i = 0; i < 8; ++i) {
        float4 av = a[i];
        #pragma unroll
        for (int j = 0; j < 8; ++j) {
          float4 bv = b[j];
          acc[i][j] = fmaf(av.x, bv.x,
                      fmaf(av.y, bv.y,
                      fmaf(av.z, bv.z,
                      fmaf(av.w, bv.w, acc[i][j]))));
        }
      }
    }
  }

  // epilogue: per-row argmin over this block's 128 cols, then global atomicMin
  #pragma unroll
  for (int i = 0; i < 8; ++i) {
    unsigned long long m = ~0ull;
    #pragma unroll
    for (int j = 0; j < 8; ++j) {
      int kk = k0 + tx + 16 * j;
      float score = h[kk] - acc[i][j];
      unsigned long long cand =
          ((unsigned long long)fkey(score) << 32) | (unsigned int)kk;
      m = (cand < m) ? cand : m;
    }
    #pragma unroll
    for (int mask = 1; mask < 16; mask <<= 1) {
      unsigned long long o = __shfl_xor(m, mask);
      m = (o < m) ? o : m;
    }
    if (tx == 0) atomicMin(&best[t0 + tyg + 16 * i], m);
  }
}

// ---------- K3: unpack index ----------
__global__ void k_extract(const unsigned long long* __restrict__ best,
                          int* __restrict__ idx) {
  int t = blockIdx.x * blockDim.x + threadIdx.x;
  if (t < T_TOKENS) idx[t] = (int)(unsigned int)(best[t] & 0xffffffffull);
}

// ---------- K4: quantized = x + value_w[idx] ----------
__global__ void k_quant(const float* __restrict__ x, const float* __restrict__ value_w,
                        const int* __restrict__ idx, float* __restrict__ q) {
  int gid = blockIdx.x * blockDim.x + threadIdx.x;  // float4 index
  int t = gid >> 7;
  int d4 = gid & 127;
  float4 xv = reinterpret_cast<const float4*>(x)[gid];
  float4 v = reinterpret_cast<const float4*>(value_w + (size_t)idx[t] * N_EMBED)[d4];
  float4 o;
  o.x = xv.x + v.x; o.y = xv.y + v.y; o.z = xv.z + v.z; o.w = xv.w + v.w;
  reinterpret_cast<float4*>(q)[gid] = o;
}

// ---------- K5: ema_n_new = DECAY*ema_n ----------
__global__ void k_scaleN(const float* __restrict__ ema_n, float* __restrict__ out_en) {
  int k = blockIdx.x * blockDim.x + threadIdx.x;
  if (k < N_TOKEN) out_en[k] = 0.99f * ema_n[k];
}

// ---------- K6: ema_w_new = DECAY*ema_w ----------
__global__ void k_scaleW(const float* __restrict__ ema_w, float* __restrict__ out_ew) {
  int gid = blockIdx.x * blockDim.x + threadIdx.x;  // float4 index
  float4 v = reinterpret_cast<const float4*>(ema_w)[gid];
  float4 o;
  o.x = 0.99f * v.x; o.y = 0.99f * v.y; o.z = 0.99f * v.z; o.w = 0.99f * v.w;
  reinterpret_cast<float4*>(out_ew)[gid] = o;
}

// ---------- K7: counts -> ema_n_new += (1-DECAY)*ratio per token ----------
__global__ void k_counts(const int* __restrict__ idx, float* __restrict__ out_en) {
  int t = blockIdx.x * blockDim.x + threadIdx.x;
  if (t < T_TOKENS) {
    const float inc = (float)(1.0 - 0.99) * 0.5f;  // (1-DECAY)*ratio
    atomicAdd(&out_en[idx[t]], inc);
  }
}

// ---------- K8: ema_w_new += (1-DECAY)*ratio * x (segment scatter) ----------
__global__ void k_scatterW(const float* __restrict__ x, const int* __restrict__ idx,
                           float* __restrict__ out_ew) {
  int gid = blockIdx.x * blockDim.x + threadIdx.x;  // float4 index over x
  int t = gid >> 7;
  int d4 = gid & 127;
  float4 xv = reinterpret_cast<const float4*>(x)[gid];
  const float c = (float)(1.0 - 0.99) * 0.5f;
  float* dst = out_ew + (size_t)idx[t] * N_EMBED + d4 * 4;
  atomicAdd(dst + 0, c * xv.x);
  atomicAdd(dst + 1, c * xv.y);
  atomicAdd(dst + 2, c * xv.z);
  atomicAdd(dst + 3, c * xv.w);
}

// ---------- K9: n = sum(ema_n_new) ----------
__global__ void k_sumn(const float* __restrict__ en, float* __restrict__ nsum) {
  __shared__ float sm[256];
  float s = 0.f;
  for (int i = threadIdx.x; i < N_TOKEN; i += 256) s += en[i];
  sm[threadIdx.x] = s;
  __syncthreads();
  for (int off = 128; off; off >>= 1) {
    if (threadIdx.x < off) sm[threadIdx.x] += sm[threadIdx.x + off];
    __syncthreads();
  }
  if (threadIdx.x == 0) *nsum = sm[0];
}

// ---------- K10: key_w_new = ema_w_new / sz ----------
__global__ void k_keyw(const float* __restrict__ out_ew, const float* __restrict__ out_en,
                       const float* __restrict__ nsum, float* __restrict__ out_kw) {
  int gid = blockIdx.x * blockDim.x + threadIdx.x;  // float4 index
  int k = gid >> 7;
  float n = *nsum;
  float sz = (out_en[k] + 1e-8f) / (n + 1e-8f * (float)N_TOKEN) * n;
  float4 w = reinterpret_cast<const float4*>(out_ew)[gid];
  float4 o;
  o.x = w.x / sz; o.y = w.y / sz; o.z = w.z / sz; o.w = w.w / sz;
  reinterpret_cast<float4*>(out_kw)[gid] = o;
}

// ---------- launcher ----------
extern "C" void kernel_launch(void* const* d_in, const int* in_sizes, int n_in,
                              void* d_out, int out_size, void* d_ws, size_t ws_size,
                              hipStream_t stream) {
  const float* x       = (const float*)d_in[0];  // [16384,512]
  const float* key_w   = (const float*)d_in[1];  // [8192,512]
  const float* value_w = (const float*)d_in[2];  // [8192,512]
  const float* ema_n   = (const float*)d_in[3];  // [8192]
  const float* ema_w   = (const float*)d_in[4];  // [8192,512]

  float* out_q  = (float*)d_out;                  // 8388608
  float* out_en = out_q + 8388608;                // 8192
  float* out_ew = out_en + N_TOKEN;               // 4194304
  float* out_kw = out_ew + 4194304;               // 4194304

  unsigned long long* best = (unsigned long long*)d_ws;           // 128 KiB
  int*   idx  = (int*)((char*)d_ws + 131072);                     // 64 KiB
  float* h    = (float*)((char*)d_ws + 196608);                   // 32 KiB
  float* nsum = (float*)((char*)d_ws + 229376);                   // 4 B

  // K1: code norms
  k_hnorm<<<N_TOKEN / 4, 256, 0, stream>>>(key_w, h);
  // init best = +inf
  hipMemsetAsync(best, 0xFF, (size_t)T_TOKENS * 8, stream);
  // K2: fused GEMM + argmin
  {
    dim3 grid(N_TOKEN / BK, T_TOKENS / BT);
    k_gemm_argmin<<<grid, 256, 0, stream>>>(x, key_w, h, best);
  }
  // K3: unpack indices
  k_extract<<<T_TOKENS / 256, 256, 0, stream>>>(best, idx);
  // K4: quantized output
  k_quant<<<(T_TOKENS * (N_EMBED / 4)) / 256, 256, 0, stream>>>(x, value_w, idx, out_q);
  // K5/K6: EMA decay bases
  k_scaleN<<<N_TOKEN / 256, 256, 0, stream>>>(ema_n, out_en);
  k_scaleW<<<(N_TOKEN * (N_EMBED / 4)) / 256, 256, 0, stream>>>(ema_w, out_ew);
  // K7: counts into ema_n_new
  k_counts<<<T_TOKENS / 256, 256, 0, stream>>>(idx, out_en);
  // K8: segment-sum scatter into ema_w_new
  k_scatterW<<<(T_TOKENS * (N_EMBED / 4)) / 256, 256, 0, stream>>>(x, idx, out_ew);
  // K9: n = sum(ema_n_new)
  k_sumn<<<1, 256, 0, stream>>>(out_en, nsum);
  // K10: renormalized keys
  k_keyw<<<(N_TOKEN * (N_EMBED / 4)) / 256, 256, 0, stream>>>(out_ew, out_en, nsum, out_kw);
}

// Round 3
// 680.850 us; speedup vs baseline: 3.0169x; 3.0169x over previous
//
#include <hip/hip_runtime.h>

#define N_TOKEN 8192
#define N_EMBED 512
#define T_TOKENS 16384
#define KP 1536   // packed K = 3 * 512

typedef __bf16 bf16x8 __attribute__((ext_vector_type(8)));
typedef __bf16 bf16x4 __attribute__((ext_vector_type(4)));
typedef float f32x4 __attribute__((ext_vector_type(4)));

// ---------- helpers ----------
__device__ __forceinline__ unsigned int fkey(float f) {
  unsigned int u = __float_as_uint(f);
  return (u & 0x80000000u) ? ~u : (u | 0x80000000u);
}

__device__ __forceinline__ void gl2lds16(const void* gsrc, void* lds) {
  __builtin_amdgcn_global_load_lds(
      (const __attribute__((address_space(1))) unsigned int*)gsrc,
      (__attribute__((address_space(3))) unsigned int*)lds, 16, 0, 0);
}

// ---------- K1: h[k] = 0.5*||key_w[k]||^2 (f32, exact norms) ----------
__global__ void k_hnorm(const float* __restrict__ key_w, float* __restrict__ h) {
  int code = blockIdx.x * 4 + (threadIdx.x >> 6);
  int lane = threadIdx.x & 63;
  const float4* row = reinterpret_cast<const float4*>(key_w + (size_t)code * N_EMBED);
  float s = 0.f;
  float4 v0 = row[lane];
  float4 v1 = row[lane + 64];
  s += v0.x*v0.x + v0.y*v0.y + v0.z*v0.z + v0.w*v0.w;
  s += v1.x*v1.x + v1.y*v1.y + v1.z*v1.z + v1.w*v1.w;
  #pragma unroll
  for (int off = 32; off; off >>= 1) s += __shfl_down(s, off);
  if (lane == 0) h[code] = 0.5f * s;
}

// ---------- pack kernels: split f32 -> [hi|hi|lo] / [hi|lo|hi] bf16 ----------
__global__ void k_pack_x(const float* __restrict__ x, __bf16* __restrict__ xp) {
  int gid = blockIdx.x * blockDim.x + threadIdx.x;  // float4 index
  int t = gid >> 7, d4 = gid & 127;
  float4 v = reinterpret_cast<const float4*>(x)[gid];
  bf16x4 hi, lo;
  hi[0] = (__bf16)v.x; hi[1] = (__bf16)v.y; hi[2] = (__bf16)v.z; hi[3] = (__bf16)v.w;
  lo[0] = (__bf16)(v.x - (float)hi[0]);
  lo[1] = (__bf16)(v.y - (float)hi[1]);
  lo[2] = (__bf16)(v.z - (float)hi[2]);
  lo[3] = (__bf16)(v.w - (float)hi[3]);
  __bf16* row = xp + (size_t)t * KP + d4 * 4;
  *(bf16x4*)(row)        = hi;
  *(bf16x4*)(row + 512)  = hi;
  *(bf16x4*)(row + 1024) = lo;
}

__global__ void k_pack_k(const float* __restrict__ kw, __bf16* __restrict__ kp) {
  int gid = blockIdx.x * blockDim.x + threadIdx.x;  // float4 index
  int n = gid >> 7, d4 = gid & 127;
  float4 v = reinterpret_cast<const float4*>(kw)[gid];
  bf16x4 hi, lo;
  hi[0] = (__bf16)v.x; hi[1] = (__bf16)v.y; hi[2] = (__bf16)v.z; hi[3] = (__bf16)v.w;
  lo[0] = (__bf16)(v.x - (float)hi[0]);
  lo[1] = (__bf16)(v.y - (float)hi[1]);
  lo[2] = (__bf16)(v.z - (float)hi[2]);
  lo[3] = (__bf16)(v.w - (float)hi[3]);
  __bf16* row = kp + (size_t)n * KP + d4 * 4;
  *(bf16x4*)(row)        = hi;
  *(bf16x4*)(row + 512)  = lo;
  *(bf16x4*)(row + 1024) = hi;
}

// ---------- K2-MFMA: bf16 MFMA GEMM (xp . kp^T) fused with argmin ----------
// score[t][k] = 0.5||k_k||^2 - x_t.k_k  (same argmin as squared distance)
#define BMr 128
#define BNr 128
#define BKe 64   // bf16 elements per K-step (128 B per row)

__global__ __launch_bounds__(256) void k_mfma_argmin(
    const __bf16* __restrict__ xp, const __bf16* __restrict__ kp,
    const float* __restrict__ h, unsigned long long* __restrict__ best) {
  __shared__ __bf16 AS[BMr * BKe];  // 16 KB, XOR-swizzled content
  __shared__ __bf16 BS[BNr * BKe];  // 16 KB

  const int nb = blockIdx.x, mb = blockIdx.y;
  const int m0 = mb * BMr, n0 = nb * BNr;
  const int tid = threadIdx.x;
  const int lane = tid & 63;
  const int wid = tid >> 6;
  const int wm = (wid >> 1) * 64, wn = (wid & 1) * 64;

  f32x4 acc[4][4] = {};

  // staging geometry (per issue i of 4): linear LDS byte off = i*4096 + tid*16
  // row = off>>7, inner = off&127 ; global src col-byte = inner ^ ((row&7)<<4)
  const int soff = tid * 16;

  for (int ks = 0; ks < KP; ks += BKe) {
    __syncthreads();  // previous iteration's ds_reads done before overwrite
    #pragma unroll
    for (int i = 0; i < 4; ++i) {
      int off = i * 4096 + soff;
      int row = off >> 7;
      int inner = (off & 127) ^ ((row & 7) << 4);
      gl2lds16(xp + (size_t)(m0 + row) * KP + ks + (inner >> 1), (char*)AS + off);
      gl2lds16(kp + (size_t)(n0 + row) * KP + ks + (inner >> 1), (char*)BS + off);
    }
    asm volatile("s_waitcnt vmcnt(0)" ::: "memory");
    __syncthreads();  // tile visible to all waves

    #pragma unroll
    for (int kk = 0; kk < 2; ++kk) {
      const int cbyte = kk * 64 + (lane >> 4) * 16;  // k-slice byte offset in row
      bf16x8 af[4], bb[4];
      #pragma unroll
      for (int i = 0; i < 4; ++i) {
        int arow = wm + i * 16 + (lane & 15);
        af[i] = *(const bf16x8*)((const char*)AS + arow * 128 + (cbyte ^ ((arow & 7) << 4)));
        int brow = wn + i * 16 + (lane & 15);
        bb[i] = *(const bf16x8*)((const char*)BS + brow * 128 + (cbyte ^ ((brow & 7) << 4)));
      }
      #pragma unroll
      for (int i = 0; i < 4; ++i)
        #pragma unroll
        for (int j = 0; j < 4; ++j)
          acc[i][j] = __builtin_amdgcn_mfma_f32_16x16x32_bf16(af[i], bb[j], acc[i][j], 0, 0, 0);
    }
  }

  // epilogue: C/D layout col = lane&15, row = (lane>>4)*4 + reg
  const int rgrp = lane >> 4;
  const int cidx = lane & 15;
  #pragma unroll
  for (int i = 0; i < 4; ++i) {
    #pragma unroll
    for (int r = 0; r < 4; ++r) {
      unsigned long long m = ~0ull;
      #pragma unroll
      for (int j = 0; j < 4; ++j) {
        int kk = n0 + wn + j * 16 + cidx;
        float score = h[kk] - acc[i][j][r];
        unsigned long long cand =
            ((unsigned long long)fkey(score) << 32) | (unsigned int)kk;
        m = (cand < m) ? cand : m;
      }
      #pragma unroll
      for (int msk = 1; msk < 16; msk <<= 1) {
        unsigned long long o = __shfl_xor(m, msk);
        m = (o < m) ? o : m;
      }
      if (cidx == 0) {
        int row = m0 + wm + i * 16 + rgrp * 4 + r;
        atomicMin(&best[row], m);
      }
    }
  }
}

// ---------- fallback f32 GEMM+argmin (used only if ws too small) ----------
#define BT 128
#define BK 128
#define DC 32
__global__ __launch_bounds__(256, 2) void k_gemm_argmin(
    const float* __restrict__ x, const float* __restrict__ key_w,
    const float* __restrict__ h, unsigned long long* __restrict__ best) {
  __shared__ float4 XS[BT * 8];
  __shared__ float4 KS[BK * 8];
  const int kb = blockIdx.x, tb = blockIdx.y;
  const int t0 = tb * BT, k0 = kb * BK;
  const int tid = threadIdx.x;
  const int tx = tid & 15;
  const int tyg = tid >> 4;
  float acc[8][8];
  #pragma unroll
  for (int i = 0; i < 8; ++i)
    #pragma unroll
    for (int j = 0; j < 8; ++j) acc[i][j] = 0.f;
  for (int dc = 0; dc < N_EMBED; dc += DC) {
    __syncthreads();
    #pragma unroll
    for (int l = 0; l < 4; ++l) {
      int li = l * 256 + tid;
      int row = li >> 3, c4 = li & 7;
      XS[row * 8 + (c4 ^ (row & 7))] =
          *reinterpret_cast<const float4*>(x + (size_t)(t0 + row) * N_EMBED + dc + c4 * 4);
      KS[row * 8 + (c4 ^ (row & 7))] =
          *reinterpret_cast<const float4*>(key_w + (size_t)(k0 + row) * N_EMBED + dc + c4 * 4);
    }
    __syncthreads();
    #pragma unroll
    for (int d4 = 0; d4 < 8; ++d4) {
      float4 a[8], b[8];
      #pragma unroll
      for (int j = 0; j < 8; ++j) {
        a[j] = XS[(tyg + 16 * j) * 8 + (d4 ^ (tyg & 7))];
        b[j] = KS[(tx  + 16 * j) * 8 + (d4 ^ (tx  & 7))];
      }
      #pragma unroll
      for (int i = 0; i < 8; ++i) {
        float4 av = a[i];
        #pragma unroll
        for (int j = 0; j < 8; ++j) {
          float4 bv = b[j];
          acc[i][j] = fmaf(av.x, bv.x, fmaf(av.y, bv.y,
                      fmaf(av.z, bv.z, fmaf(av.w, bv.w, acc[i][j]))));
        }
      }
    }
  }
  #pragma unroll
  for (int i = 0; i < 8; ++i) {
    unsigned long long m = ~0ull;
    #pragma unroll
    for (int j = 0; j < 8; ++j) {
      int kk = k0 + tx + 16 * j;
      float score = h[kk] - acc[i][j];
      unsigned long long cand =
          ((unsigned long long)fkey(score) << 32) | (unsigned int)kk;
      m = (cand < m) ? cand : m;
    }
    #pragma unroll
    for (int mask = 1; mask < 16; mask <<= 1) {
      unsigned long long o = __shfl_xor(m, mask);
      m = (o < m) ? o : m;
    }
    if (tx == 0) atomicMin(&best[t0 + tyg + 16 * i], m);
  }
}

// ---------- K3: unpack index ----------
__global__ void k_extract(const unsigned long long* __restrict__ best,
                          int* __restrict__ idx) {
  int t = blockIdx.x * blockDim.x + threadIdx.x;
  if (t < T_TOKENS) idx[t] = (int)(unsigned int)(best[t] & 0xffffffffull);
}

// ---------- K4: quantized = x + value_w[idx] ----------
__global__ void k_quant(const float* __restrict__ x, const float* __restrict__ value_w,
                        const int* __restrict__ idx, float* __restrict__ q) {
  int gid = blockIdx.x * blockDim.x + threadIdx.x;
  int t = gid >> 7;
  int d4 = gid & 127;
  float4 xv = reinterpret_cast<const float4*>(x)[gid];
  float4 v = reinterpret_cast<const float4*>(value_w + (size_t)idx[t] * N_EMBED)[d4];
  float4 o;
  o.x = xv.x + v.x; o.y = xv.y + v.y; o.z = xv.z + v.z; o.w = xv.w + v.w;
  reinterpret_cast<float4*>(q)[gid] = o;
}

// ---------- K5/K6: EMA decay bases ----------
__global__ void k_scaleN(const float* __restrict__ ema_n, float* __restrict__ out_en) {
  int k = blockIdx.x * blockDim.x + threadIdx.x;
  if (k < N_TOKEN) out_en[k] = 0.99f * ema_n[k];
}
__global__ void k_scaleW(const float* __restrict__ ema_w, float* __restrict__ out_ew) {
  int gid = blockIdx.x * blockDim.x + threadIdx.x;
  float4 v = reinterpret_cast<const float4*>(ema_w)[gid];
  float4 o;
  o.x = 0.99f * v.x; o.y = 0.99f * v.y; o.z = 0.99f * v.z; o.w = 0.99f * v.w;
  reinterpret_cast<float4*>(out_ew)[gid] = o;
}

// ---------- K7: counts ----------
__global__ void k_counts(const int* __restrict__ idx, float* __restrict__ out_en) {
  int t = blockIdx.x * blockDim.x + threadIdx.x;
  if (t < T_TOKENS) {
    const float inc = (float)(1.0 - 0.99) * 0.5f;  // (1-DECAY)*ratio
    atomicAdd(&out_en[idx[t]], inc);
  }
}

// ---------- K8: segment-sum scatter ----------
__global__ void k_scatterW(const float* __restrict__ x, const int* __restrict__ idx,
                           float* __restrict__ out_ew) {
  int gid = blockIdx.x * blockDim.x + threadIdx.x;
  int t = gid >> 7;
  int d4 = gid & 127;
  float4 xv = reinterpret_cast<const float4*>(x)[gid];
  const float c = (float)(1.0 - 0.99) * 0.5f;
  float* dst = out_ew + (size_t)idx[t] * N_EMBED + d4 * 4;
  atomicAdd(dst + 0, c * xv.x);
  atomicAdd(dst + 1, c * xv.y);
  atomicAdd(dst + 2, c * xv.z);
  atomicAdd(dst + 3, c * xv.w);
}

// ---------- K9: n = sum(ema_n_new) ----------
__global__ void k_sumn(const float* __restrict__ en, float* __restrict__ nsum) {
  __shared__ float sm[256];
  float s = 0.f;
  for (int i = threadIdx.x; i < N_TOKEN; i += 256) s += en[i];
  sm[threadIdx.x] = s;
  __syncthreads();
  for (int off = 128; off; off >>= 1) {
    if (threadIdx.x < off) sm[threadIdx.x] += sm[threadIdx.x + off];
    __syncthreads();
  }
  if (threadIdx.x == 0) *nsum = sm[0];
}

// ---------- K10: key_w_new = ema_w_new / sz ----------
__global__ void k_keyw(const float* __restrict__ out_ew, const float* __restrict__ out_en,
                       const float* __restrict__ nsum, float* __restrict__ out_kw) {
  int gid = blockIdx.x * blockDim.x + threadIdx.x;
  int k = gid >> 7;
  float n = *nsum;
  float sz = (out_en[k] + 1e-8f) / (n + 1e-8f * (float)N_TOKEN) * n;
  float4 w = reinterpret_cast<const float4*>(out_ew)[gid];
  float4 o;
  o.x = w.x / sz; o.y = w.y / sz; o.z = w.z / sz; o.w = w.w / sz;
  reinterpret_cast<float4*>(out_kw)[gid] = o;
}

// ---------- launcher ----------
extern "C" void kernel_launch(void* const* d_in, const int* in_sizes, int n_in,
                              void* d_out, int out_size, void* d_ws, size_t ws_size,
                              hipStream_t stream) {
  const float* x       = (const float*)d_in[0];
  const float* key_w   = (const float*)d_in[1];
  const float* value_w = (const float*)d_in[2];
  const float* ema_n   = (const float*)d_in[3];
  const float* ema_w   = (const float*)d_in[4];

  float* out_q  = (float*)d_out;
  float* out_en = out_q + 8388608;
  float* out_ew = out_en + N_TOKEN;
  float* out_kw = out_ew + 4194304;

  unsigned long long* best = (unsigned long long*)d_ws;          // 128 KiB
  int*   idx  = (int*)((char*)d_ws + 131072);                    // 64 KiB
  float* h    = (float*)((char*)d_ws + 196608);                  // 32 KiB
  float* nsum = (float*)((char*)d_ws + 229376);                  // 4 B
  __bf16* xp  = (__bf16*)((char*)d_ws + 262144);                 // 48 MiB
  __bf16* kp  = (__bf16*)((char*)d_ws + 262144 + (size_t)T_TOKENS * KP * 2);  // 24 MiB
  const size_t ws_need = 262144 + (size_t)T_TOKENS * KP * 2 + (size_t)N_TOKEN * KP * 2;

  k_hnorm<<<N_TOKEN / 4, 256, 0, stream>>>(key_w, h);
  hipMemsetAsync(best, 0xFF, (size_t)T_TOKENS * 8, stream);

  if (ws_size >= ws_need) {
    k_pack_x<<<(T_TOKENS * (N_EMBED / 4)) / 256, 256, 0, stream>>>(x, xp);
    k_pack_k<<<(N_TOKEN * (N_EMBED / 4)) / 256, 256, 0, stream>>>(key_w, kp);
    dim3 grid(N_TOKEN / BNr, T_TOKENS / BMr);
    k_mfma_argmin<<<grid, 256, 0, stream>>>(xp, kp, h, best);
  } else {
    dim3 grid(N_TOKEN / BK, T_TOKENS / BT);
    k_gemm_argmin<<<grid, 256, 0, stream>>>(x, key_w, h, best);
  }

  k_extract<<<T_TOKENS / 256, 256, 0, stream>>>(best, idx);
  k_quant<<<(T_TOKENS * (N_EMBED / 4)) / 256, 256, 0, stream>>>(x, value_w, idx, out_q);
  k_scaleN<<<N_TOKEN / 256, 256, 0, stream>>>(ema_n, out_en);
  k_scaleW<<<(N_TOKEN * (N_EMBED / 4)) / 256, 256, 0, stream>>>(ema_w, out_ew);
  k_counts<<<T_TOKENS / 256, 256, 0, stream>>>(idx, out_en);
  k_scatterW<<<(T_TOKENS * (N_EMBED / 4)) / 256, 256, 0, stream>>>(x, idx, out_ew);
  k_sumn<<<1, 256, 0, stream>>>(out_en, nsum);
  k_keyw<<<(N_TOKEN * (N_EMBED / 4)) / 256, 256, 0, stream>>>(out_ew, out_en, nsum, out_kw);
}